// Round 16
// baseline (455.816 us; speedup 1.0000x reference)
//
#include <hip/hip_runtime.h>
#include <cstddef>

constexpr int N0 = 16384, N1 = 4096, N2 = 1024, N3 = 256;
constexpr int E0 = 6 * N0, E1 = 6 * N1, E2 = 6 * N2, E3 = 6 * N3;
constexpr int ETOT = E0 + E1 + E2 + E3; // 129024
constexpr int LOCN = 32 * N0;           // 524288

// ---- workspace layout (4-byte units) ----
constexpr size_t O_CNT  = 0;          // 21760 int (zeroed with stats by memset)
constexpr size_t O_STAT = 21760;      // 384 f: g0|g1|g2|l0|l1|l2 (x64)
constexpr size_t O_BK   = 22144;      // buckets: A0@+0, A1@+524288, A2@+655360, A3@+688128
constexpr size_t O_YL0  = 718464;
constexpr size_t O_XL1  = O_YL0 + 524288;
constexpr size_t O_YL1  = O_XL1 + 524288;
constexpr size_t O_XL2  = O_YL1 + 524288;
constexpr size_t O_YL2  = O_XL2 + 524288;
constexpr size_t O_XL3  = O_YL2 + 524288;
constexpr size_t O_YL3  = O_XL3 + 524288;  // 49152
constexpr size_t O_YG0  = O_YL3 + 49152;   // 8192
constexpr size_t O_XG1  = O_YG0 + 8192;
constexpr size_t O_XWG1 = O_XG1 + 8192;
constexpr size_t O_YG1  = O_XWG1 + 8192;   // 32768
constexpr size_t O_XG2  = O_YG1 + 32768;
constexpr size_t O_XWG2 = O_XG2 + 32768;
constexpr size_t O_YG2  = O_XWG2 + 32768;  // 131072
constexpr size_t O_XG3  = O_YG2 + 131072;  // 131072
constexpr size_t O_XW3  = O_XG3 + 131072;  // 12288
constexpr size_t O_YG3  = O_XW3 + 12288;   // 49152
constexpr size_t O_PART = O_YG3 + 49152;   // 49152

struct Params {
    const float *z, *lin_w, *lin_b, *loc_w, *loc_b, *Wg, *bg, *Wg3, *bg3;
    const float *Wl, *bl, *Wl3, *bl3, *gam_g, *bet_g, *gam_l, *bet_l;
    const float *U0, *U1, *U2, *U3;
    const int *A0, *A1, *A2, *A3;
    float* ws;
    float* out;
};

// ============ bucket-CSR fill (one pass, all 4 graphs; R13-validated) ============
__device__ void fill_edges(const Params& P, int rb, int nrb) {
    int* cnt = (int*)(P.ws + O_CNT);
    int* bk  = (int*)(P.ws + O_BK);
    for (int e = rb * 256 + threadIdx.x; e < ETOT; e += nrb * 256) {
        const int* A; int E, co, bo; int x = e;
        if (x < E0)              { A = P.A0; E = E0; co = 0;     bo = 0; }
        else if ((x -= E0) < E1) { A = P.A1; E = E1; co = 16384; bo = 524288; }
        else if ((x -= E1) < E2) { A = P.A2; E = E2; co = 20480; bo = 655360; }
        else { x -= E2;            A = P.A3; E = E3; co = 21504; bo = 688128; }
        int s = A[x], d = A[E + x];
        int slot = atomicAdd(cnt + co + d, 1);
        if (slot < 32) bk[bo + d * 32 + slot] = s;
    }
}

// ============ lin head + rank-1 U3 level -> YG0 (R13-validated) ============
__device__ void lin_u3(const Params& P, float* sm) {
    float* zl  = sm;         // 128
    float* xl  = sm + 128;   // 32
    float* xw0 = sm + 160;   // 32
    int t = threadIdx.x;
    if (t < 128) zl[t] = P.z[t];
    __syncthreads();
    if (t < 32) {
        float s = P.lin_b[t];
        for (int k = 0; k < 128; k++) s += zl[k] * P.lin_w[k * 160 + t];
        xl[t] = s;
    }
    __syncthreads();
    if (t < 32) {
        float s = 0.f;
        for (int k = 0; k < 32; k++) s += xl[k] * P.Wg[k * 32 + t];
        xw0[t] = s;
    }
    __syncthreads();
    float rs = 0.f;
    for (int k = 0; k < 64; k++) rs += P.U3[t * 64 + k];
    float* y = P.ws + O_YG0;
    for (int f = 0; f < 32; f++) y[t * 32 + f] = rs * xw0[f];
    __syncthreads();
}

// ============ mv: setup (self-computed xlz + Wl0) then per-chunk body ============
__device__ void mv_setup(const Params& P, float* sm) {
    float* xs = sm;            // 128
    float* Wl = sm + 1152;     // 1024
    float* zl = sm + 2176;     // 128
    int t = threadIdx.x;
    for (int i = t; i < 1024; i += 256) Wl[i] = P.Wl[i];
    if (t < 128) zl[t] = P.z[t];
    __syncthreads();
    if (t < 128) {
        float s = P.lin_b[32 + t];
#pragma unroll 8
        for (int k = 0; k < 128; k++) s += zl[k] * P.lin_w[k * 160 + 32 + t];
        xs[t] = s;
    }
    __syncthreads();
}

__device__ void mv_chunk(const Params& P, int mb, float* sm) {
    float* xs   = sm;          // 128
    float* xrow = sm + 128;    // 1024
    float* Wl   = sm + 1152;   // 1024
    int t = threadIdx.x;
    size_t j0 = (size_t)mb * 1024 + t * 4;
    float4 acc = *(const float4*)(P.loc_b + j0);
#pragma unroll 8
    for (int k = 0; k < 128; k++) {
        float xk = xs[k];
        float4 w = *(const float4*)(P.loc_w + (size_t)k * LOCN + j0);
        acc.x += xk * w.x; acc.y += xk * w.y; acc.z += xk * w.z; acc.w += xk * w.w;
    }
    *(float4*)(xrow + t * 4) = acc;
    __syncthreads();
    float* yl0 = P.ws + O_YL0;
#pragma unroll
    for (int q = 0; q < 4; q++) {
        int idx = q * 256 + t;
        int nn = idx >> 5, f = idx & 31;
        float s = 0.f;
        const float* xr = xrow + nn * 32;
#pragma unroll
        for (int k = 0; k < 32; k++) s += xr[k] * Wl[k * 32 + f];
        yl0[(size_t)mb * 1024 + idx] = s;
    }
    __syncthreads();
}

// ============ bucket gather (F=32) + bias + BN stats (R13-validated) ============
__device__ void gatherB(const int* cnt, const int* bk, const float* y,
                        const float* bias, int n, float* xout, float* stats,
                        int rb, int nrb, float* sm) {
    int t = threadIdx.x, f = t & 31, half = (t >> 5) & 1, w = t >> 6;
    float bf = bias[f];
    float s = 0.f, ss = 0.f;
    for (int node = rb * 8 + w; node < n; node += nrb * 8) {
        int c = cnt[node];
        int cl = c < 32 ? c : 32;
        const int* b = bk + (size_t)node * 32;
        float a = half ? 0.f : y[(size_t)node * 32 + f];
        for (int r = half; r < cl; r += 2)
            a += y[(size_t)b[r] * 32 + f];
        a += __shfl_down(a, 32, 64);
        if (!half) {
            float v = a / (float)(c + 1) + bf;
            xout[(size_t)node * 32 + f] = v;
            s += v; ss += v * v;
        }
    }
    if (t < 64) sm[t] = 0.f;
    __syncthreads();
    if (!half) { atomicAdd(sm + f, s); atomicAdd(sm + 32 + f, ss); }
    __syncthreads();
    if (t < 64) atomicAdd(stats + t, sm[t]);
}

// ============ BN + leakyReLU + row @ W(32xFO), 512 threads (validated) ============
template <int FO>
__device__ void bnxw512(const float* xin, const float* stats, const float* gam,
                        const float* bet, const float* W, float invn, int n,
                        float* out, int rb, float* sm) {
    float* Wl = sm;
    float* sc = sm + 32 * FO;
    float* sh = sc + 32;
    int t = threadIdx.x;
    for (int i = t; i < 32 * FO; i += 512) Wl[i] = W[i];
    if (t < 32) {
        float mu = stats[t] * invn;
        float var = stats[32 + t] * invn - mu * mu;
        float rs = rsqrtf(var + 1e-5f);
        float scv = rs * gam[t];
        sc[t] = scv; sh[t] = bet[t] - mu * scv;
    }
    __syncthreads();
    int node = rb * 512 + t;
    if (node < n) {
        float x[32];
        const float4* xp = (const float4*)(xin + (size_t)node * 32);
#pragma unroll
        for (int j = 0; j < 8; j++) {
            float4 v = xp[j];
            x[4 * j] = v.x; x[4 * j + 1] = v.y; x[4 * j + 2] = v.z; x[4 * j + 3] = v.w;
        }
#pragma unroll
        for (int k = 0; k < 32; k++) {
            float v = sc[k] * x[k] + sh[k];
            x[k] = v > 0.f ? v : 0.01f * v;
        }
        float yv[FO];
#pragma unroll
        for (int q = 0; q < FO; q++) {
            float s = 0.f;
#pragma unroll
            for (int k = 0; k < 32; k++) s += x[k] * Wl[k * FO + q];
            yv[q] = s;
        }
        float* yp = out + (size_t)node * FO;
#pragma unroll
        for (int q = 0; q < FO; q++) yp[q] = yv[q];
    }
}

// ============ y = U(64 rows) @ xw(m x 32), 512 threads (validated) ============
__device__ void gemm512(const float* U, const float* xw, int m, float* y,
                        int rb, float* sm) {
    float* ut = sm;          // 64*64
    float* xt = sm + 4096;   // 64*32
    int t = threadIdx.x, f = t & 31, rg = t >> 5;
    int r0 = rb * 64;
    float a0 = 0, a1 = 0, a2 = 0, a3 = 0;
    for (int k0 = 0; k0 < m; k0 += 64) {
        {
            int row = t >> 3, c0 = (t & 7) * 8;
            const float* src = U + (size_t)(r0 + row) * m + k0 + c0;
            *(float4*)(ut + row * 64 + c0) = *(const float4*)src;
            *(float4*)(ut + row * 64 + c0 + 4) = *(const float4*)(src + 4);
        }
        {
            int kk = t >> 3, c0 = (t & 7) * 4;
            *(float4*)(xt + kk * 32 + c0) =
                *(const float4*)(xw + (size_t)(k0 + kk) * 32 + c0);
        }
        __syncthreads();
#pragma unroll
        for (int kk = 0; kk < 64; kk++) {
            float xv = xt[kk * 32 + f];
            a0 += ut[rg * 64 + kk] * xv;
            a1 += ut[(rg + 16) * 64 + kk] * xv;
            a2 += ut[(rg + 32) * 64 + kk] * xv;
            a3 += ut[(rg + 48) * 64 + kk] * xv;
        }
        __syncthreads();
    }
    y[(size_t)(r0 + rg) * 32 + f] = a0;
    y[(size_t)(r0 + rg + 16) * 32 + f] = a1;
    y[(size_t)(r0 + rg + 32) * 32 + f] = a2;
    y[(size_t)(r0 + rg + 48) * 32 + f] = a3;
}

// ================= D1: [fill|lin_u3 prefix] + mv x2 chunks  (256 x 256) ======
__global__ void __launch_bounds__(256) k_mv(Params P) {
    __shared__ float sm[2304];
    int bid = blockIdx.x;
    if (bid < 32)       fill_edges(P, bid, 32);
    else if (bid == 32) lin_u3(P, sm);
    mv_setup(P, sm);
    mv_chunk(P, 2 * bid, sm);
    mv_chunk(P, 2 * bid + 1, sm);
}

// ================= D2: g_l0 | g_g0  (244 x 512) ======
__global__ void __launch_bounds__(512) k_d2(Params P) {
    __shared__ float sm[64];
    int bid = blockIdx.x;
    float* ws = P.ws;
    const int* cnt = (int*)(ws + O_CNT);
    const int* bk  = (int*)(ws + O_BK);
    if (bid < 240)
        gatherB(cnt, bk, ws + O_YL0, P.bl, N0, ws + O_XL1, ws + O_STAT + 192,
                bid, 240, sm);
    else
        gatherB(cnt + 21504, bk + 688128, ws + O_YG0, P.bg, N3, ws + O_XG1,
                ws + O_STAT, bid - 240, 4, sm);
}

// ================= D3: bn_l0 | bn_g0  (33 x 512) ======
__global__ void __launch_bounds__(512) k_d3(Params P) {
    __shared__ float sm[1152];
    int bid = blockIdx.x;
    float* ws = P.ws;
    if (bid < 32)
        bnxw512<32>(ws + O_XL1, ws + O_STAT + 192, P.gam_l, P.bet_l, P.Wl + 1024,
                    1.f / N0, N0, ws + O_YL1, bid, sm);
    else
        bnxw512<32>(ws + O_XG1, ws + O_STAT, P.gam_g, P.bet_g, P.Wg + 1024,
                    1.f / N3, N3, ws + O_XWG1, 0, sm);
}

// ================= D4: g_l1 | gemmU2  (256 x 512) ======
__global__ void __launch_bounds__(512) k_d4(Params P) {
    __shared__ float sm[6144];
    int bid = blockIdx.x;
    float* ws = P.ws;
    const int* cnt = (int*)(ws + O_CNT);
    const int* bk  = (int*)(ws + O_BK);
    if (bid < 240)
        gatherB(cnt, bk, ws + O_YL1, P.bl + 32, N0, ws + O_XL2,
                ws + O_STAT + 256, bid, 240, sm);
    else
        gemm512(P.U2, ws + O_XWG1, 256, ws + O_YG1, bid - 240, sm);
}

// ================= D5: bn_l1 | g_g1(A2)  (48 x 512) ======
__global__ void __launch_bounds__(512) k_d5(Params P) {
    __shared__ float sm[1152];
    int bid = blockIdx.x;
    float* ws = P.ws;
    const int* cnt = (int*)(ws + O_CNT);
    const int* bk  = (int*)(ws + O_BK);
    if (bid < 32)
        bnxw512<32>(ws + O_XL2, ws + O_STAT + 256, P.gam_l + 32, P.bet_l + 32,
                    P.Wl + 2048, 1.f / N0, N0, ws + O_YL2, bid, sm);
    else
        gatherB(cnt + 20480, bk + 655360, ws + O_YG1, P.bg + 32, N2,
                ws + O_XG2, ws + O_STAT + 64, bid - 32, 16, sm);
}

// ================= D6: g_l2 | bn_g1  (242 x 512) ======
__global__ void __launch_bounds__(512) k_d6(Params P) {
    __shared__ float sm[1152];
    int bid = blockIdx.x;
    float* ws = P.ws;
    const int* cnt = (int*)(ws + O_CNT);
    const int* bk  = (int*)(ws + O_BK);
    if (bid < 240)
        gatherB(cnt, bk, ws + O_YL2, P.bl + 64, N0, ws + O_XL3,
                ws + O_STAT + 320, bid, 240, sm);
    else
        bnxw512<32>(ws + O_XG2, ws + O_STAT + 64, P.gam_g + 32, P.bet_g + 32,
                    P.Wg + 2048, 1.f / N2, N2, ws + O_XWG2, bid - 240, sm);
}

// ================= D7: bn_l2 (FO=3) | gemmU1  (96 x 512) ======
__global__ void __launch_bounds__(512) k_d7(Params P) {
    __shared__ float sm[6144];
    int bid = blockIdx.x;
    float* ws = P.ws;
    if (bid < 32)
        bnxw512<3>(ws + O_XL3, ws + O_STAT + 320, P.gam_l + 64, P.bet_l + 64,
                   P.Wl3, 1.f / N0, N0, ws + O_YL3, bid, sm);
    else
        gemm512(P.U1, ws + O_XWG2, 1024, ws + O_YG2, bid - 32, sm);
}

// ================= D8: g_g2(A1) | final-local partial  (144 x 512) ======
__global__ void __launch_bounds__(512) k_d8(Params P) {
    __shared__ float sm[64];
    int bid = blockIdx.x;
    float* ws = P.ws;
    const int* cnt = (int*)(ws + O_CNT);
    const int* bk  = (int*)(ws + O_BK);
    if (bid < 16) {
        gatherB(cnt + 16384, bk + 524288, ws + O_YG2, P.bg + 64, N1,
                ws + O_XG3, ws + O_STAT + 128, bid, 16, sm);
    } else {
        // partial_l[node,r] = (yl3[self] + sum bucket yl3) / (c+1)
        int idx = (bid - 16) * 512 + threadIdx.x;  // 65536 = 16384*4
        int node = idx >> 2, r = idx & 3;
        if (r < 3) {
            const float* yl = ws + O_YL3;
            int c = cnt[node];
            int cl = c < 32 ? c : 32;
            const int* b = bk + (size_t)node * 32;
            float a = yl[node * 3 + r];
            for (int e = 0; e < cl; e++) a += yl[b[e] * 3 + r];
            (ws + O_PART)[node * 3 + r] = a / (float)(c + 1);
        }
    }
}

// ================= D9: bn_g2 (FO=3)  (8 x 512) ======
__global__ void __launch_bounds__(512) k_d9(Params P) {
    __shared__ float sm[256];
    bnxw512<3>(P.ws + O_XG3, P.ws + O_STAT + 128, P.gam_g + 64, P.bet_g + 64,
               P.Wg3, 1.f / N1, N1, P.ws + O_XW3, blockIdx.x, sm);
}

// ====== D10: yg3 = U0 @ xw3 — 2-phase K-split, 24KB LDS, 2 blocks/CU ======
__global__ void __launch_bounds__(256) k_u0(Params P) {
    __shared__ float pl[6144]; // 24 KB: one K-half of xw3, swizzled
    int t = threadIdx.x, w = t >> 6, lane = t & 63;
    const float* xw3 = P.ws + O_XW3;
    float* y = P.ws + O_YG3;
    float a0[8], a1[8], a2[8];
#pragma unroll
    for (int r = 0; r < 8; r++) { a0[r] = 0.f; a1[r] = 0.f; a2[r] = 0.f; }
    int row0 = blockIdx.x * 32 + w * 8;
    for (int ph = 0; ph < 2; ph++) {
        __syncthreads();
        for (int i = t; i < 6144; i += 256) {
            int k = i / 3, h = i - 3 * k;       // k in [0,2048)
            pl[h * 2048 + ((k & 3) << 9) + (k >> 2)] = xw3[(ph * 2048 + k) * 3 + h];
        }
        __syncthreads();
#pragma unroll
        for (int r = 0; r < 8; r++) {
            const float4* up = (const float4*)(P.U0 + (size_t)(row0 + r) * 4096 + ph * 2048);
#pragma unroll 4
            for (int c = 0; c < 8; c++) {
                float4 u = up[c * 64 + lane];
                int b = c * 64 + lane;          // [0,512)
                a0[r] += u.x * pl[b]        + u.y * pl[512 + b]  + u.z * pl[1024 + b] + u.w * pl[1536 + b];
                a1[r] += u.x * pl[2048 + b] + u.y * pl[2560 + b] + u.z * pl[3072 + b] + u.w * pl[3584 + b];
                a2[r] += u.x * pl[4096 + b] + u.y * pl[4608 + b] + u.z * pl[5120 + b] + u.w * pl[5632 + b];
            }
        }
    }
#pragma unroll
    for (int r = 0; r < 8; r++) {
        for (int o = 32; o; o >>= 1) {
            a0[r] += __shfl_down(a0[r], o, 64);
            a1[r] += __shfl_down(a1[r], o, 64);
            a2[r] += __shfl_down(a2[r], o, 64);
        }
        if (lane == 0) {
            y[(row0 + r) * 3]     = a0[r];
            y[(row0 + r) * 3 + 1] = a1[r];
            y[(row0 + r) * 3 + 2] = a2[r];
        }
    }
}

// ================= D11: final: gather yg3 + combine with partial (256 x 256) ====
__global__ void __launch_bounds__(256) k_fin(Params P) {
    int t = blockIdx.x * 256 + threadIdx.x;
    int node = t >> 2, r = t & 3;
    if (node >= N0 || r >= 3) return;
    float* ws = P.ws;
    const int* cnt = (int*)(ws + O_CNT);
    const int* bk  = (int*)(ws + O_BK) + (size_t)node * 32;
    const float* yg = ws + O_YG3;
    int c = cnt[node];
    int cl = c < 32 ? c : 32;
    float ag = yg[node * 3 + r];
    for (int e = 0; e < cl; e++) ag += yg[bk[e] * 3 + r];
    float inv = 1.f / (float)(c + 1);
    P.out[node * 3 + r] = 0.01f * (ag * inv + P.bg3[r]) +
                          0.99f * ((ws + O_PART)[node * 3 + r] + P.bl3[r]);
}

extern "C" void kernel_launch(void* const* d_in, const int* in_sizes, int n_in,
                              void* d_out, int out_size, void* d_ws, size_t ws_size,
                              hipStream_t stream) {
    Params p;
    p.z     = (const float*)d_in[0];
    p.lin_w = (const float*)d_in[1];
    p.lin_b = (const float*)d_in[2];
    p.loc_w = (const float*)d_in[3];
    p.loc_b = (const float*)d_in[4];
    p.Wg    = (const float*)d_in[5];
    p.bg    = (const float*)d_in[8];
    p.Wg3   = (const float*)d_in[9];
    p.bg3   = (const float*)d_in[12];
    p.Wl    = (const float*)d_in[13];
    p.bl    = (const float*)d_in[16];
    p.Wl3   = (const float*)d_in[17];
    p.bl3   = (const float*)d_in[20];
    p.gam_g = (const float*)d_in[21];
    p.bet_g = (const float*)d_in[22];
    p.gam_l = (const float*)d_in[23];
    p.bet_l = (const float*)d_in[24];
    p.U0    = (const float*)d_in[25];
    p.U1    = (const float*)d_in[26];
    p.U2    = (const float*)d_in[27];
    p.U3    = (const float*)d_in[28];
    p.A0    = (const int*)d_in[29];
    p.A1    = (const int*)d_in[30];
    p.A2    = (const int*)d_in[31];
    p.A3    = (const int*)d_in[32];
    p.ws    = (float*)d_ws;
    p.out   = (float*)d_out;

    hipMemsetAsync(d_ws, 0, (21760 + 384) * 4, stream);  // cnt + stats
    k_mv <<<256, 256, 0, stream>>>(p);  // fill|lin_u3 + all 512 mv chunks
    k_d2 <<<244, 512, 0, stream>>>(p);  // g_l0 | g_g0
    k_d3 <<<33,  512, 0, stream>>>(p);  // bn_l0 | bn_g0
    k_d4 <<<256, 512, 0, stream>>>(p);  // g_l1 | gemmU2
    k_d5 <<<48,  512, 0, stream>>>(p);  // bn_l1 | g_g1
    k_d6 <<<242, 512, 0, stream>>>(p);  // g_l2 | bn_g1
    k_d7 <<<96,  512, 0, stream>>>(p);  // bn_l2 | gemmU1
    k_d8 <<<144, 512, 0, stream>>>(p);  // g_g2 | final-local partial
    k_d9 <<<8,   512, 0, stream>>>(p);  // bn_g2
    k_u0 <<<512, 256, 0, stream>>>(p);  // U0 @ xw3 (2-phase, 2 blocks/CU)
    k_fin<<<256, 256, 0, stream>>>(p);  // final combine
}

// Round 17
// 393.417 us; speedup vs baseline: 1.1586x; 1.1586x over previous
//
#include <hip/hip_runtime.h>
#include <cstddef>

constexpr int N0 = 16384, N1 = 4096, N2 = 1024, N3 = 256;
constexpr int E0 = 6 * N0, E1 = 6 * N1, E2 = 6 * N2, E3 = 6 * N3;
constexpr int ETOT = E0 + E1 + E2 + E3; // 129024
constexpr int LOCN = 32 * N0;           // 524288

// ---- workspace layout (float offsets) ----
constexpr size_t O_XLZ  = 0;
constexpr size_t O_STAT = 128;      // 6 slots x 64 (sum|sumsq)
constexpr size_t O_XW0  = 512;      // 64x32 bcast
constexpr size_t O_YG0  = 2560;     // 256x32
constexpr size_t O_XG1  = 10752;
constexpr size_t O_XWG1 = 18944;
constexpr size_t O_YG1  = 27136;    // 1024x32
constexpr size_t O_XG2  = 59904;
constexpr size_t O_XWG2 = 92672;
constexpr size_t O_YG2  = 125440;   // 4096x32
constexpr size_t O_XG3  = 256512;
constexpr size_t O_XW3  = 387584;   // 4096x3
constexpr size_t O_YG3  = 399872;   // 16384x3
constexpr size_t O_DEG  = 449024;   // ints
constexpr size_t O_RP   = 470784;
constexpr size_t O_CUR  = 492548;
constexpr size_t O_EIDX = 514312;
constexpr size_t O_YL0  = 1169408;  // 16384x32
constexpr size_t O_XL1  = 1693696;
constexpr size_t O_YL1  = 2217984;
constexpr size_t O_XL2  = 2742272;
constexpr size_t O_YL2  = 3266560;
constexpr size_t O_XL3  = 3790848;
constexpr size_t O_YL3  = 4315136;  // 16384x3

struct Params {
    const float *z, *lin_w, *lin_b, *loc_w, *loc_b, *Wg, *bg, *Wg3, *bg3;
    const float *Wl, *bl, *Wl3, *bl3, *gam_g, *bet_g, *gam_l, *bet_l;
    const float *U0, *U1, *U2, *U3;
    const int *A0, *A1, *A2, *A3;
    float* ws;
    float* out;
};

// ================= K1: pre (zero deg/stats + linear head) =================
__global__ void __launch_bounds__(256) k_pre(Params P) {
    int t = threadIdx.x, b = blockIdx.x;
    float* ws = P.ws;
    if (b < 64) {
        int* deg = (int*)(ws + O_DEG);
        for (int i = b * 256 + t; i < 21760; i += 64 * 256) deg[i] = 0;
        if (b == 1) for (int i = t; i < 384; i += 256) (ws + O_STAT)[i] = 0.f;
        return;
    }
    __shared__ float zl[128];
    __shared__ float xl[160];
    __shared__ float xwl[32];
    if (t < 128) zl[t] = P.z[t];
    __syncthreads();
    if (t < 160) {
        float s = P.lin_b[t];
        for (int k = 0; k < 128; k++) s += zl[k] * P.lin_w[k * 160 + t];
        xl[t] = s;
    }
    __syncthreads();
    if (t < 128) (ws + O_XLZ)[t] = xl[32 + t];
    if (t < 32) {
        float s = 0.f;
        for (int k = 0; k < 32; k++) s += xl[k] * P.Wg[k * 32 + t];
        xwl[t] = s;
    }
    __syncthreads();
    for (int i = t; i < 2048; i += 256) (ws + O_XW0)[i] = xwl[i & 31];
}

// ============ device: fused matvec + @Wl0 (one 1024-output chunk) ============
__device__ void matvec_y(const Params& P, int mb, float* sm) {
    float* xs = sm;          // 128
    float* xrow = sm + 128;  // 1024
    float* Wl = sm + 1152;   // 1024
    int t = threadIdx.x;
    if (t < 128) xs[t] = (P.ws + O_XLZ)[t];
    for (int i = t; i < 1024; i += 256) Wl[i] = P.Wl[i];
    __syncthreads();
    size_t j0 = (size_t)mb * 1024 + t * 4;
    float4 acc = *(const float4*)(P.loc_b + j0);
#pragma unroll 8
    for (int k = 0; k < 128; k++) {
        float xk = xs[k];
        float4 w = *(const float4*)(P.loc_w + (size_t)k * LOCN + j0);
        acc.x += xk * w.x; acc.y += xk * w.y; acc.z += xk * w.z; acc.w += xk * w.w;
    }
    *(float4*)(xrow + t * 4) = acc;
    __syncthreads();
    float* yl0 = P.ws + O_YL0;
#pragma unroll
    for (int q = 0; q < 4; q++) {
        int idx = q * 256 + t;
        int nn = idx >> 5, f = idx & 31;
        float s = 0.f;
        const float* xr = xrow + nn * 32;
#pragma unroll
        for (int k = 0; k < 32; k++) s += xr[k] * Wl[k * 32 + f];
        yl0[(size_t)mb * 1024 + idx] = s;
    }
}

// ================= K2: matvec[0:191) | hist | U3 gemm  (256 blocks) =================
__global__ void __launch_bounds__(256) k_l2(Params P) {
    __shared__ float sm[2304];
    int t = threadIdx.x, bid = blockIdx.x;
    float* ws = P.ws;
    if (bid < 191) {
        matvec_y(P, bid, sm);
    } else if (bid < 255) {
        int* deg = (int*)(ws + O_DEG);
        for (int e = (bid - 191) * 256 + t; e < ETOT; e += 64 * 256) {
            const int* A; int E, dofs; int x = e;
            if (x < E0)              { A = P.A0; E = E0; dofs = 0; }
            else if ((x -= E0) < E1) { A = P.A1; E = E1; dofs = 16384; }
            else if ((x -= E1) < E2) { A = P.A2; E = E2; dofs = 20480; }
            else { x -= E2;            A = P.A3; E = E3; dofs = 21504; }
            atomicAdd(deg + dofs + A[E + x], 1);
        }
    } else {
        for (int i = t; i < 2048; i += 256) sm[i] = (ws + O_XW0)[i];
        __syncthreads();
        float acc[32];
#pragma unroll
        for (int f = 0; f < 32; f++) acc[f] = 0.f;
        for (int k = 0; k < 64; k++) {
            float u = P.U3[t * 64 + k];
#pragma unroll
            for (int f = 0; f < 32; f++) acc[f] += u * sm[k * 32 + f];
        }
        float* yp = ws + O_YG0 + t * 32;
#pragma unroll
        for (int f = 0; f < 32; f++) yp[f] = acc[f];
    }
}

// ================= K3: matvec[191:443) | scan  (256 blocks) =================
__global__ void __launch_bounds__(256) k_l3(Params P) {
    __shared__ float sm[2304];
    int t = threadIdx.x, bid = blockIdx.x;
    float* ws = P.ws;
    if (bid < 252) {
        matvec_y(P, 191 + bid, sm);
    } else {
        int g = bid - 252;
        int n   = g == 0 ? N0 : g == 1 ? N1 : g == 2 ? N2 : N3;
        int db  = g == 0 ? 0 : g == 1 ? 16384 : g == 2 ? 20480 : 21504;
        int rbo = g == 0 ? 0 : g == 1 ? 16385 : g == 2 ? 20482 : 21507;
        int per = n >> 8;
        const int* d = (int*)(ws + O_DEG) + db;
        int* rpp = (int*)(ws + O_RP) + rbo;
        int* cup = (int*)(ws + O_CUR) + rbo;
        int s = 0;
        for (int i = 0; i < per; i++) s += d[t * per + i];
        int* part = (int*)sm;
        part[t] = s;
        __syncthreads();
        for (int off = 1; off < 256; off <<= 1) {
            int v = (t >= off) ? part[t - off] : 0;
            __syncthreads();
            part[t] += v;
            __syncthreads();
        }
        int run = t ? part[t - 1] : 0;
        for (int i = 0; i < per; i++) {
            int idx = t * per + i;
            rpp[idx] = run; cup[idx] = run;
            run += d[idx];
        }
        if (t == 255) rpp[n] = part[255];
    }
}

// ================= K4: matvec[443:512) | CSR fill  (133 blocks) =================
__global__ void __launch_bounds__(256) k_l4(Params P) {
    __shared__ float sm[2304];
    int t = threadIdx.x, bid = blockIdx.x;
    float* ws = P.ws;
    if (bid < 69) {
        matvec_y(P, 443 + bid, sm);
    } else {
        int* cur  = (int*)(ws + O_CUR);
        int* eidx = (int*)(ws + O_EIDX);
        for (int e = (bid - 69) * 256 + t; e < ETOT; e += 64 * 256) {
            const int* A; int E, cofs, eofs; int x = e;
            if (x < E0)              { A = P.A0; E = E0; cofs = 0;     eofs = 0; }
            else if ((x -= E0) < E1) { A = P.A1; E = E1; cofs = 16385; eofs = 98304; }
            else if ((x -= E1) < E2) { A = P.A2; E = E2; cofs = 20482; eofs = 122880; }
            else { x -= E2;            A = P.A3; E = E3; cofs = 21507; eofs = 129024; }
            int srcn = A[x], dd = A[E + x];
            int slot = atomicAdd(cur + cofs + dd, 1);
            eidx[eofs + slot] = srcn;
        }
    }
}

// ============ device: pull gather (F=32) + bias + BN stats ============
__device__ void gatherG(const int* rp, const int* ei, const float* y,
                        const float* bias, int n, float* xout, float* stats,
                        int rb, int nrb, float* sm) {
    int t = threadIdx.x, f = t & 31, half = (t >> 5) & 1, w = t >> 6;
    float bf = bias[f];
    float s = 0.f, ss = 0.f;
    for (int node = rb * 8 + w; node < n; node += nrb * 8) {
        int r0 = rp[node], r1 = rp[node + 1];
        float a = half ? 0.f : y[(size_t)node * 32 + f];
        for (int r = r0 + half; r < r1; r += 2)
            a += y[(size_t)ei[r] * 32 + f];
        a += __shfl_down(a, 32, 64);
        if (!half) {
            float v = a / (float)(r1 - r0 + 1) + bf;
            xout[(size_t)node * 32 + f] = v;
            s += v; ss += v * v;
        }
    }
    if (t < 64) sm[t] = 0.f;
    __syncthreads();
    if (!half) { atomicAdd(sm + f, s); atomicAdd(sm + 32 + f, ss); }
    __syncthreads();
    if (t < 64) atomicAdd(stats + t, sm[t]);
}

// ============ device: BN + leakyReLU + row @ W(32xFO), 512 threads ============
template <int FO>
__device__ void bnxw512(const float* xin, const float* stats, const float* gam,
                        const float* bet, const float* W, float invn, int n,
                        float* out, int rb, float* sm) {
    float* Wl = sm;
    float* sc = sm + 32 * FO;
    float* sh = sc + 32;
    int t = threadIdx.x;
    for (int i = t; i < 32 * FO; i += 512) Wl[i] = W[i];
    if (t < 32) {
        float mu = stats[t] * invn;
        float var = stats[32 + t] * invn - mu * mu;
        float rs = rsqrtf(var + 1e-5f);
        float scv = rs * gam[t];
        sc[t] = scv; sh[t] = bet[t] - mu * scv;
    }
    __syncthreads();
    int node = rb * 512 + t;
    if (node < n) {
        float x[32];
        const float4* xp = (const float4*)(xin + (size_t)node * 32);
#pragma unroll
        for (int j = 0; j < 8; j++) {
            float4 v = xp[j];
            x[4 * j] = v.x; x[4 * j + 1] = v.y; x[4 * j + 2] = v.z; x[4 * j + 3] = v.w;
        }
#pragma unroll
        for (int k = 0; k < 32; k++) {
            float v = sc[k] * x[k] + sh[k];
            x[k] = v > 0.f ? v : 0.01f * v;
        }
        float yv[FO];
#pragma unroll
        for (int q = 0; q < FO; q++) {
            float s = 0.f;
#pragma unroll
            for (int k = 0; k < 32; k++) s += x[k] * Wl[k * FO + q];
            yv[q] = s;
        }
        float* yp = out + (size_t)node * FO;
#pragma unroll
        for (int q = 0; q < FO; q++) yp[q] = yv[q];
    }
}

// ============ device: y = U(64 rows) @ xw(m x 32), 512 threads ============
__device__ void gemm512(const float* U, const float* xw, int m, float* y,
                        int rb, float* sm) {
    float* ut = sm;          // 64*64
    float* xt = sm + 4096;   // 64*32
    int t = threadIdx.x, f = t & 31, rg = t >> 5; // rg 0..15
    int r0 = rb * 64;
    float a0 = 0, a1 = 0, a2 = 0, a3 = 0;
    for (int k0 = 0; k0 < m; k0 += 64) {
        {
            int row = t >> 3, c0 = (t & 7) * 8;
            const float* src = U + (size_t)(r0 + row) * m + k0 + c0;
            *(float4*)(ut + row * 64 + c0) = *(const float4*)src;
            *(float4*)(ut + row * 64 + c0 + 4) = *(const float4*)(src + 4);
        }
        {
            int kk = t >> 3, c0 = (t & 7) * 4;
            *(float4*)(xt + kk * 32 + c0) =
                *(const float4*)(xw + (size_t)(k0 + kk) * 32 + c0);
        }
        __syncthreads();
#pragma unroll
        for (int kk = 0; kk < 64; kk++) {
            float xv = xt[kk * 32 + f];
            a0 += ut[rg * 64 + kk] * xv;
            a1 += ut[(rg + 16) * 64 + kk] * xv;
            a2 += ut[(rg + 32) * 64 + kk] * xv;
            a3 += ut[(rg + 48) * 64 + kk] * xv;
        }
        __syncthreads();
    }
    y[(size_t)(r0 + rg) * 32 + f] = a0;
    y[(size_t)(r0 + rg + 16) * 32 + f] = a1;
    y[(size_t)(r0 + rg + 32) * 32 + f] = a2;
    y[(size_t)(r0 + rg + 48) * 32 + f] = a3;
}

// ================= K5: gather_l0 | gather_g0  (256 blocks) =================
__global__ void __launch_bounds__(512) k_l5(Params P) {
    __shared__ float sm[64];
    int bid = blockIdx.x;
    float* ws = P.ws;
    const int* rp = (int*)(ws + O_RP);
    const int* ei = (int*)(ws + O_EIDX);
    if (bid < 240)
        gatherG(rp, ei, ws + O_YL0, P.bl, N0, ws + O_XL1, ws + O_STAT + 192,
                bid, 240, sm);
    else
        gatherG(rp + 21507, ei + 129024, ws + O_YG0, P.bg, N3, ws + O_XG1,
                ws + O_STAT, bid - 240, 16, sm);
}

// ================= K6: bnxw_l0 | bnxw_g0  (33 blocks) =================
__global__ void __launch_bounds__(512) k_l6(Params P) {
    __shared__ float sm[1152];
    int bid = blockIdx.x;
    float* ws = P.ws;
    if (bid < 32)
        bnxw512<32>(ws + O_XL1, ws + O_STAT + 192, P.gam_l, P.bet_l, P.Wl + 1024,
                    1.f / N0, N0, ws + O_YL1, bid, sm);
    else
        bnxw512<32>(ws + O_XG1, ws + O_STAT, P.gam_g, P.bet_g, P.Wg + 1024,
                    1.f / N3, N3, ws + O_XWG1, bid - 32, sm);
}

// ================= K7: gather_l1 | gemm_g1 (U2)  (256 blocks) =================
__global__ void __launch_bounds__(512) k_l7(Params P) {
    __shared__ float sm[6144];
    int bid = blockIdx.x;
    float* ws = P.ws;
    const int* rp = (int*)(ws + O_RP);
    const int* ei = (int*)(ws + O_EIDX);
    if (bid < 240)
        gatherG(rp, ei, ws + O_YL1, P.bl + 32, N0, ws + O_XL2,
                ws + O_STAT + 256, bid, 240, sm);
    else
        gemm512(P.U2, ws + O_XWG1, 256, ws + O_YG1, bid - 240, sm);
}

// ================= K8: bnxw_l1 | gather_g1  (48 blocks) =================
__global__ void __launch_bounds__(512) k_l8(Params P) {
    __shared__ float sm[1152];
    int bid = blockIdx.x;
    float* ws = P.ws;
    const int* rp = (int*)(ws + O_RP);
    const int* ei = (int*)(ws + O_EIDX);
    if (bid < 32)
        bnxw512<32>(ws + O_XL2, ws + O_STAT + 256, P.gam_l + 32, P.bet_l + 32,
                    P.Wl + 2048, 1.f / N0, N0, ws + O_YL2, bid, sm);
    else
        gatherG(rp + 20482, ei + 122880, ws + O_YG1, P.bg + 32, N2,
                ws + O_XG2, ws + O_STAT + 64, bid - 32, 16, sm);
}

// ================= K9: gather_l2 | bnxw_g1  (242 blocks) =================
__global__ void __launch_bounds__(512) k_l9(Params P) {
    __shared__ float sm[1152];
    int bid = blockIdx.x;
    float* ws = P.ws;
    const int* rp = (int*)(ws + O_RP);
    const int* ei = (int*)(ws + O_EIDX);
    if (bid < 240)
        gatherG(rp, ei, ws + O_YL2, P.bl + 64, N0, ws + O_XL3,
                ws + O_STAT + 320, bid, 240, sm);
    else
        bnxw512<32>(ws + O_XG2, ws + O_STAT + 64, P.gam_g + 32, P.bet_g + 32,
                    P.Wg + 2048, 1.f / N2, N2, ws + O_XWG2, bid - 240, sm);
}

// ================= K10: bnxw_l2 (FO=3) | gemm_g2 (U1)  (96 blocks) =================
__global__ void __launch_bounds__(512) k_l10(Params P) {
    __shared__ float sm[6144];
    int bid = blockIdx.x;
    float* ws = P.ws;
    if (bid < 32)
        bnxw512<3>(ws + O_XL3, ws + O_STAT + 320, P.gam_l + 64, P.bet_l + 64,
                   P.Wl3, 1.f / N0, N0, ws + O_YL3, bid, sm);
    else
        gemm512(P.U1, ws + O_XWG2, 1024, ws + O_YG2, bid - 32, sm);
}

// ================= K11: gather_g2  (64 blocks) =================
__global__ void __launch_bounds__(512) k_l11(Params P) {
    __shared__ float sm[64];
    float* ws = P.ws;
    const int* rp = (int*)(ws + O_RP);
    const int* ei = (int*)(ws + O_EIDX);
    gatherG(rp + 16385, ei + 98304, ws + O_YG2, P.bg + 64, N1,
            ws + O_XG3, ws + O_STAT + 128, blockIdx.x, 64, sm);
}

// ================= K12: bnxw_g2 (FO=3)  (8 blocks) =================
__global__ void __launch_bounds__(512) k_l12(Params P) {
    __shared__ float sm[256];
    bnxw512<3>(P.ws + O_XG3, P.ws + O_STAT + 128, P.gam_g + 64, P.bet_g + 64,
               P.Wg3, 1.f / N1, N1, P.ws + O_XW3, blockIdx.x, sm);
}

// ================= K13: yg3 = U0 @ xw3  (256 blocks, 64 rows each) =================
__global__ void __launch_bounds__(256) k_gemmU3(Params P) {
    __shared__ float pl[3 * 4096];
    int t = threadIdx.x;
    const float* xw3 = P.ws + O_XW3;
    float* y = P.ws + O_YG3;
    for (int i = t; i < 12288; i += 256) {
        int k = i / 3, h = i - 3 * k;
        pl[h * 4096 + ((k & 3) << 10) + (k >> 2)] = xw3[i];
    }
    __syncthreads();
    int w = t >> 6, lane = t & 63;
    for (int it = 0; it < 4; it++) {
        for (int rr = 0; rr < 4; rr++) {
            int row = it * 4096 + blockIdx.x * 16 + w * 4 + rr;
            const float4* up = (const float4*)(P.U0 + (size_t)row * 4096);
            float a0 = 0, a1 = 0, a2 = 0;
#pragma unroll 4
            for (int c = 0; c < 16; c++) {
                float4 u = up[c * 64 + lane];
                int b = c * 64 + lane;
                a0 += u.x * pl[b]        + u.y * pl[1024 + b]  + u.z * pl[2048 + b]   + u.w * pl[3072 + b];
                a1 += u.x * pl[4096 + b] + u.y * pl[5120 + b]  + u.z * pl[6144 + b]   + u.w * pl[7168 + b];
                a2 += u.x * pl[8192 + b] + u.y * pl[9216 + b]  + u.z * pl[10240 + b]  + u.w * pl[11264 + b];
            }
            for (int o = 32; o; o >>= 1) {
                a0 += __shfl_down(a0, o, 64);
                a1 += __shfl_down(a1, o, 64);
                a2 += __shfl_down(a2, o, 64);
            }
            if (lane == 0) { y[row * 3] = a0; y[row * 3 + 1] = a1; y[row * 3 + 2] = a2; }
        }
    }
}

// ================= K14: final combine over A0  (256 blocks) =================
__global__ void __launch_bounds__(256) k_final(Params P) {
    int t = blockIdx.x * 256 + threadIdx.x;
    int node = t >> 2, r = t & 3;
    if (node >= N0 || r >= 3) return;
    float* ws = P.ws;
    const int* rp = (int*)(ws + O_RP);
    const int* ei = (int*)(ws + O_EIDX);
    const float* yg = ws + O_YG3;
    const float* yl = ws + O_YL3;
    int r0 = rp[node], r1 = rp[node + 1];
    float ag = yg[node * 3 + r], al = yl[node * 3 + r];
    int e = r0;
    for (; e + 4 <= r1; e += 4) {
        int s0 = ei[e], s1 = ei[e + 1], s2 = ei[e + 2], s3 = ei[e + 3];
        ag += yg[s0 * 3 + r] + yg[s1 * 3 + r] + yg[s2 * 3 + r] + yg[s3 * 3 + r];
        al += yl[s0 * 3 + r] + yl[s1 * 3 + r] + yl[s2 * 3 + r] + yl[s3 * 3 + r];
    }
    for (; e < r1; e++) { ag += yg[ei[e] * 3 + r]; al += yl[ei[e] * 3 + r]; }
    float inv = 1.f / (float)(r1 - r0 + 1);
    P.out[node * 3 + r] = 0.01f * (ag * inv + P.bg3[r]) + 0.99f * (al * inv + P.bl3[r]);
}

extern "C" void kernel_launch(void* const* d_in, const int* in_sizes, int n_in,
                              void* d_out, int out_size, void* d_ws, size_t ws_size,
                              hipStream_t stream) {
    Params p;
    p.z     = (const float*)d_in[0];
    p.lin_w = (const float*)d_in[1];
    p.lin_b = (const float*)d_in[2];
    p.loc_w = (const float*)d_in[3];
    p.loc_b = (const float*)d_in[4];
    p.Wg    = (const float*)d_in[5];
    p.bg    = (const float*)d_in[8];
    p.Wg3   = (const float*)d_in[9];
    p.bg3   = (const float*)d_in[12];
    p.Wl    = (const float*)d_in[13];
    p.bl    = (const float*)d_in[16];
    p.Wl3   = (const float*)d_in[17];
    p.bl3   = (const float*)d_in[20];
    p.gam_g = (const float*)d_in[21];
    p.bet_g = (const float*)d_in[22];
    p.gam_l = (const float*)d_in[23];
    p.bet_l = (const float*)d_in[24];
    p.U0    = (const float*)d_in[25];
    p.U1    = (const float*)d_in[26];
    p.U2    = (const float*)d_in[27];
    p.U3    = (const float*)d_in[28];
    p.A0    = (const int*)d_in[29];
    p.A1    = (const int*)d_in[30];
    p.A2    = (const int*)d_in[31];
    p.A3    = (const int*)d_in[32];
    p.ws    = (float*)d_ws;
    p.out   = (float*)d_out;

    k_pre   <<<65,  256, 0, stream>>>(p);
    k_l2    <<<256, 256, 0, stream>>>(p);  // matvec 0:191 | hist | U3 gemm
    k_l3    <<<256, 256, 0, stream>>>(p);  // matvec 191:443 | scan
    k_l4    <<<133, 256, 0, stream>>>(p);  // matvec 443:512 | fill
    k_l5    <<<256, 512, 0, stream>>>(p);  // gather_l0 | gather_g0
    k_l6    <<<33,  512, 0, stream>>>(p);  // bnxw_l0 | bnxw_g0
    k_l7    <<<256, 512, 0, stream>>>(p);  // gather_l1 | gemm_g1
    k_l8    <<<48,  512, 0, stream>>>(p);  // bnxw_l1 | gather_g1
    k_l9    <<<242, 512, 0, stream>>>(p);  // gather_l2 | bnxw_g1
    k_l10   <<<96,  512, 0, stream>>>(p);  // bnxw_l2 | gemm_g2
    k_l11   <<<64,  512, 0, stream>>>(p);  // gather_g2
    k_l12   <<<8,   512, 0, stream>>>(p);  // bnxw_g2
    k_gemmU3<<<256, 256, 0, stream>>>(p);  // U0 @ xw3
    k_final <<<256, 256, 0, stream>>>(p);  // combine
}